// Round 4
// baseline (867.117 us; speedup 1.0000x reference)
//
#include <hip/hip_runtime.h>
#include <hip/hip_bf16.h>
#include <cstdint>
#include <math.h>

// Problem constants: B=2,S=2048,E=2048,H=16,KH=4,G=4,D=128,F=8192, M=B*S=4096
typedef unsigned short u16;
using f32x4   = __attribute__((ext_vector_type(4))) float;
using short8  = __attribute__((ext_vector_type(8))) short;
using short4v = __attribute__((ext_vector_type(4))) short;

#define DEV static __device__ __forceinline__

DEV u16 f2bf(float f) {  // RNE f32 -> bf16
  union { float f; unsigned u; } v; v.f = f;
  unsigned r = v.u + 0x7fffu + ((v.u >> 16) & 1u);
  return (u16)(r >> 16);
}

DEV f32x4 mfma_bf16(short8 a, short8 b, f32x4 c) {
  return __builtin_amdgcn_mfma_f32_16x16x32_bf16(a, b, c, 0, 0, 0);
}

DEV void gload16(const void* g, void* l) {  // async global->LDS, 16B/lane, LDS base wave-uniform
  __builtin_amdgcn_global_load_lds((const __attribute__((address_space(1))) void*)g,
                                   (__attribute__((address_space(3))) void*)l,
                                   16, 0, 0);
}

// ---------------- transpose + f32->bf16 convert: out[n][k] = bf16(in[k][n]) ----
__global__ __launch_bounds__(256) void transpose_cvt(
    const float* __restrict__ in, u16* __restrict__ out, int K, int N)
{
  __shared__ float tile[32][33];
  const int n0 = blockIdx.x * 32, k0 = blockIdx.y * 32;
  const int c = threadIdx.x & 31, r = threadIdx.x >> 5;  // r in 0..7
#pragma unroll
  for (int i = 0; i < 4; i++) {
    const int row = r + i * 8;
    tile[row][c] = in[(size_t)(k0 + row) * N + n0 + c];
  }
  __syncthreads();
#pragma unroll
  for (int i = 0; i < 4; i++) {
    const int row = r + i * 8;
    out[(size_t)(n0 + row) * K + k0 + c] = f2bf(tile[c][row]);
  }
}

// ---------------- LayerNorm (f32 in, bf16 out), one row (2048) per block ------
__global__ __launch_bounds__(256) void ln_kernel(
    const float* __restrict__ x, const float* __restrict__ g,
    const float* __restrict__ bt, u16* __restrict__ out)
{
  __shared__ float red1[4], red2[4];
  const int row = blockIdx.x;
  const int t = threadIdx.x;
  const int lane = t & 63, w = t >> 6;
  const float* xr = x + (size_t)row * 2048 + t * 8;
  float v[8];
  {
    const float4* p4 = (const float4*)xr;
    float4 a = p4[0], b = p4[1];
    v[0] = a.x; v[1] = a.y; v[2] = a.z; v[3] = a.w;
    v[4] = b.x; v[5] = b.y; v[6] = b.z; v[7] = b.w;
  }
  float s = 0.f;
#pragma unroll
  for (int j = 0; j < 8; j++) s += v[j];
#pragma unroll
  for (int m = 1; m < 64; m <<= 1) s += __shfl_xor(s, m);
  if (lane == 0) red1[w] = s;
  __syncthreads();
  const float mu = (red1[0] + red1[1] + red1[2] + red1[3]) * (1.f / 2048.f);
  float q = 0.f;
#pragma unroll
  for (int j = 0; j < 8; j++) { v[j] -= mu; q += v[j] * v[j]; }
#pragma unroll
  for (int m = 1; m < 64; m <<= 1) q += __shfl_xor(q, m);
  if (lane == 0) red2[w] = q;
  __syncthreads();
  const float rstd = rsqrtf((red2[0] + red2[1] + red2[2] + red2[3]) * (1.f / 2048.f) + 1e-5f);
  const float4* g4 = (const float4*)(g + t * 8);
  const float4* b4 = (const float4*)(bt + t * 8);
  float4 ga = g4[0], gb = g4[1], ba = b4[0], bb = b4[1];
  float gg[8] = {ga.x, ga.y, ga.z, ga.w, gb.x, gb.y, gb.z, gb.w};
  float bbv[8] = {ba.x, ba.y, ba.z, ba.w, bb.x, bb.y, bb.z, bb.w};
  short8 o;
#pragma unroll
  for (int j = 0; j < 8; j++) o[j] = (short)f2bf(v[j] * rstd * gg[j] + bbv[j]);
  *(short8*)&out[(size_t)row * 2048 + t * 8] = o;
}

// ---------------- small GEMM (kept for K/V, N=512): 128x128, 4 waves ----------
// MODE: 1=K(bias,bf16) 2=V(bias, write transposed [d][s])
template<int MODE, int N, int K>
__global__ void __launch_bounds__(256) gemm_bt(
    const u16* __restrict__ A, const u16* __restrict__ Bt,
    const float* __restrict__ bias,
    u16* __restrict__ out_bf)
{
  __shared__ u16 As[128 * 64];
  __shared__ u16 Bs[128 * 64];
  const int m0 = blockIdx.y * 128;
  const int n0 = blockIdx.x * 128;
  const int tid = threadIdx.x;
  const int lane = tid & 63, w = tid >> 6;
  const int wm = w >> 1, wn = w & 1;
  const int z = lane >> 4, l15 = lane & 15;

  f32x4 acc[4][4];
#pragma unroll
  for (int m = 0; m < 4; m++)
#pragma unroll
    for (int n = 0; n < 4; n++)
#pragma unroll
      for (int i = 0; i < 4; i++) acc[m][n][i] = 0.f;

  for (int k0 = 0; k0 < K; k0 += 64) {
#pragma unroll
    for (int j = 0; j < 4; j++) {
      const int seg = w * 4 + j;
      const int c = seg * 64 + lane;
      const int r = c >> 3;
      const int cc = (c & 7) ^ (r & 7);           // source pre-swizzle
      gload16(A + (size_t)(m0 + r) * K + k0 + cc * 8, &As[seg * 512]);
    }
#pragma unroll
    for (int j = 0; j < 4; j++) {
      const int seg = w * 4 + j;
      const int c = seg * 64 + lane;
      const int r = c >> 3;
      const int cc = (c & 7) ^ (r & 7);
      gload16(Bt + (size_t)(n0 + r) * K + k0 + cc * 8, &Bs[seg * 512]);
    }
    asm volatile("s_waitcnt vmcnt(0)" ::: "memory");
    __syncthreads();

#pragma unroll
    for (int kk = 0; kk < 2; kk++) {
      short8 af[4], bfr[4];
#pragma unroll
      for (int m = 0; m < 4; m++) {
        const int row = wm * 64 + m * 16 + l15;
        const int off = row * 64 + ((kk * 32 + z * 8) ^ ((row & 7) << 3));
        af[m] = *(const short8*)&As[off];
      }
#pragma unroll
      for (int n = 0; n < 4; n++) {
        const int row = wn * 64 + n * 16 + l15;
        const int off = row * 64 + ((kk * 32 + z * 8) ^ ((row & 7) << 3));
        bfr[n] = *(const short8*)&Bs[off];
      }
#pragma unroll
      for (int m = 0; m < 4; m++)
#pragma unroll
        for (int n = 0; n < 4; n++)
          acc[m][n] = mfma_bf16(af[m], bfr[n], acc[m][n]);
    }
    __syncthreads();
  }

#pragma unroll
  for (int m = 0; m < 4; m++) {
    const int row0 = m0 + wm * 64 + m * 16 + z * 4;
#pragma unroll
    for (int n = 0; n < 4; n++) {
      const int col = n0 + wn * 64 + n * 16 + l15;
      f32x4 v = acc[m][n];
      const float bb = bias[col];
      if constexpr (MODE == 1) {
#pragma unroll
        for (int i = 0; i < 4; i++)
          out_bf[(size_t)(row0 + i) * N + col] = f2bf(v[i] + bb);
      } else {
        const int bidx = row0 >> 11, sidx = row0 & 2047;
        const int kh = col >> 7, d = col & 127;
        short4v p;
#pragma unroll
        for (int i = 0; i < 4; i++) p[i] = (short)f2bf(v[i] + bb);
        *(short4v*)&out_bf[(size_t)((bidx * 4 + kh) * 128 + d) * 2048 + sidx] = p;
      }
    }
  }
}

// ---------------- big GEMM: counted-vmcnt deep pipeline, 8 waves, BN=256 ------
// Phase = 32 K-cols (group). 4 LDS slots (2 tiles). Prologue stages groups 0-2;
// phase p: vmcnt(2L) -> barrier -> stage(p+3) -> ds_read -> lgkmcnt(0)+schedbar
// -> MFMA (setprio) -> barrier. Tail: vmcnt(2L)/vmcnt(L)/vmcnt(0). Loads never
// drain in-loop; each group has 3 phases (~600cy) in flight. Conflict-free XOR
// swizzle (g ^= (r>>1)&3), pre-swizzled global source (both-sides rule).
// MODE: 0=Q(bias,*scale,bf16) 3=O(bias+resid,f32) 4=U(bias+gelu,bf16) 5=D(bias+accum,f32)
template<int MODE, int BM, int N, int K>
__global__ void __launch_bounds__(512) gemm256(
    const u16* __restrict__ A, const u16* __restrict__ Bt,
    const float* __restrict__ bias, const float* __restrict__ resid,
    u16* __restrict__ out_bf, float* __restrict__ out_f)
{
  constexpr int BN = 256;
  constexpr int MREP = BM / 32;          // A frags per wave
  constexpr int LA = BM / 128;           // A gloads per thread per group
  constexpr int P = K / 32;              // phases (one group each)
  constexpr int NWG = (4096 / BM) * (N / BN);
  constexpr int CPX = NWG / 8;

  __shared__ u16 Al[4][BM * 32];
  __shared__ u16 Bl[4][BN * 32];

  const int bid = blockIdx.x;
  const int wg = (bid & 7) * CPX + (bid >> 3);   // XCD-contiguous chunks
  const int bm = wg / (N / BN), bn = wg % (N / BN);
  const int m0 = bm * BM, n0 = bn * BN;
  const int tid = threadIdx.x, lane = tid & 63, w = tid >> 6;
  const int wm = w >> 2, wn = w & 3;
  const int z = lane >> 4, l15 = lane & 15;
  const int wmBase = wm * (BM / 2);
  const int wnBase = wn * 64;
  const int koff = (z ^ ((l15 >> 1) & 3)) * 8;          // reader swizzle (const/thread)
  const int col8 = ((lane & 3) ^ ((lane >> 3) & 3)) * 8; // source pre-swizzle
  const int srow = lane >> 2;

  f32x4 acc[MREP][4];
#pragma unroll
  for (int m = 0; m < MREP; m++)
#pragma unroll
    for (int n = 0; n < 4; n++)
#pragma unroll
      for (int i = 0; i < 4; i++) acc[m][n][i] = 0.f;

  auto stage = [&](int g) {
    const int sl = g & 3;
    const int kc = g * 32;
#pragma unroll
    for (int j = 0; j < LA; j++) {
      const int sweep = w * LA + j;
      gload16(A + (size_t)(m0 + sweep * 16 + srow) * K + kc + col8, &Al[sl][sweep * 512]);
    }
#pragma unroll
    for (int j = 0; j < 2; j++) {
      const int sweep = w * 2 + j;
      gload16(Bt + (size_t)(n0 + sweep * 16 + srow) * K + kc + col8, &Bl[sl][sweep * 512]);
    }
  };

#define PHASE(pp, VMSTR, DOSTAGE)                                              \
  do {                                                                         \
    asm volatile("s_waitcnt " VMSTR ::: "memory");                             \
    __builtin_amdgcn_s_barrier();                                              \
    asm volatile("" ::: "memory");                                             \
    if (DOSTAGE) stage((pp) + 3);                                              \
    const int sl_ = (pp) & 3;                                                  \
    const u16* Ab_ = &Al[sl_][0];                                              \
    const u16* Bb_ = &Bl[sl_][0];                                              \
    short8 af_[MREP], bf_[4];                                                  \
    _Pragma("unroll")                                                          \
    for (int m = 0; m < MREP; m++)                                             \
      af_[m] = *(const short8*)&Ab_[(wmBase + m * 16 + l15) * 32 + koff];      \
    _Pragma("unroll")                                                          \
    for (int n = 0; n < 4; n++)                                                \
      bf_[n] = *(const short8*)&Bb_[(wnBase + n * 16 + l15) * 32 + koff];      \
    asm volatile("s_waitcnt lgkmcnt(0)" ::: "memory");                         \
    __builtin_amdgcn_sched_barrier(0);                                         \
    __builtin_amdgcn_s_setprio(1);                                             \
    _Pragma("unroll")                                                          \
    for (int m = 0; m < MREP; m++)                                             \
      _Pragma("unroll")                                                        \
      for (int n = 0; n < 4; n++)                                              \
        acc[m][n] = mfma_bf16(af_[m], bf_[n], acc[m][n]);                      \
    __builtin_amdgcn_s_setprio(0);                                             \
    asm volatile("" ::: "memory");                                             \
    __builtin_amdgcn_s_barrier();                                              \
  } while (0)

  stage(0); stage(1); stage(2);

  if constexpr (LA == 2) {               // L=4: vmcnt 8/4/0
    for (int p = 0; p < P - 3; p++) PHASE(p, "vmcnt(8)", true);
    PHASE(P - 3, "vmcnt(8)", false);
    PHASE(P - 2, "vmcnt(4)", false);
    PHASE(P - 1, "vmcnt(0)", false);
  } else {                               // L=3: vmcnt 6/3/0
    for (int p = 0; p < P - 3; p++) PHASE(p, "vmcnt(6)", true);
    PHASE(P - 3, "vmcnt(6)", false);
    PHASE(P - 2, "vmcnt(3)", false);
    PHASE(P - 1, "vmcnt(0)", false);
  }
#undef PHASE

#pragma unroll
  for (int m = 0; m < MREP; m++) {
    const int row0 = m0 + wmBase + m * 16 + z * 4;
#pragma unroll
    for (int n = 0; n < 4; n++) {
      const int col = n0 + wnBase + n * 16 + l15;
      f32x4 v = acc[m][n];
      const float bb = bias[col];
      if constexpr (MODE == 0) {
#pragma unroll
        for (int i = 0; i < 4; i++)
          out_bf[(size_t)(row0 + i) * N + col] = f2bf((v[i] + bb) * 0.08838834764831845f);
      } else if constexpr (MODE == 3) {
#pragma unroll
        for (int i = 0; i < 4; i++) {
          const size_t idx = (size_t)(row0 + i) * N + col;
          out_f[idx] = v[i] + bb + resid[idx];
        }
      } else if constexpr (MODE == 4) {
#pragma unroll
        for (int i = 0; i < 4; i++) {
          const float xx = v[i] + bb;
          out_bf[(size_t)(row0 + i) * N + col] =
              f2bf(0.5f * xx * (1.f + erff(xx * 0.70710678118654752f)));
        }
      } else {
#pragma unroll
        for (int i = 0; i < 4; i++) {
          const size_t idx = (size_t)(row0 + i) * N + col;
          out_f[idx] = v[i] + bb + out_f[idx];
        }
      }
    }
  }
}

// ---------------- Flash attention, causal, GQA. 128 q-rows/block, 4 waves -----
__global__ void __launch_bounds__(256) attn_kernel(
    const u16* __restrict__ qb, const u16* __restrict__ kb,
    const u16* __restrict__ vt, u16* __restrict__ ob)
{
  __shared__ u16 Kt[2][64 * 128];
  __shared__ u16 Vs[2][128 * 64];
  __shared__ u16 Pl[4 * 32 * 64];

  const int idx = blockIdx.x;
  const int xcd = idx & 7;
  const int u = (idx >> 3) & 31;
  const int half = idx >> 8;
  const int bh = xcd * 4 + (u & 3);       // 4 bh per XCD -> one (b,kh) KV set
  const int qh = u >> 2;                  // 0..7
  const int qt = half ? (15 - qh) : qh;   // complementary pairing: i <-> i+256

  const int b = bh >> 4, h = bh & 15, kh = h >> 2;
  const int q0 = qt * 128;
  const int tid = threadIdx.x, lane = tid & 63, w = tid >> 6;
  const int z = lane >> 4, l15 = lane & 15;
  const int qw0 = q0 + w * 32;
  const int ksw = (l15 & 7) << 3;         // read-side XOR swizzle

  short8 qf[2][4];
#pragma unroll
  for (int m = 0; m < 2; m++)
#pragma unroll
    for (int kk = 0; kk < 4; kk++)
      qf[m][kk] = *(const short8*)&qb[(size_t)(b * 2048 + qw0 + m * 16 + l15) * 2048 +
                                      h * 128 + kk * 32 + z * 8];

  f32x4 oacc[2][8];
#pragma unroll
  for (int m = 0; m < 2; m++)
#pragma unroll
    for (int n = 0; n < 8; n++)
#pragma unroll
      for (int i = 0; i < 4; i++) oacc[m][n][i] = 0.f;
  float mst[2][4], lst[2][4];
#pragma unroll
  for (int m = 0; m < 2; m++)
#pragma unroll
    for (int i = 0; i < 4; i++) { mst[m][i] = -1e30f; lst[m][i] = 0.f; }

  auto STAGE = [&](int tt, int bufsel) {
    const int kv0s = tt * 64;
#pragma unroll
    for (int j = 0; j < 4; j++) {               // K tile (rows=kv, 128 d)
      const int seg = w * 4 + j;
      const int c = seg * 64 + lane;
      const int r = c >> 4;
      const int cc = (c & 15) ^ (r & 7);
      gload16(kb + (size_t)(b * 2048 + kv0s + r) * 512 + kh * 128 + cc * 8,
              &Kt[bufsel][seg * 512]);
    }
#pragma unroll
    for (int j = 0; j < 4; j++) {               // V^T tile (rows=d, 64 kv)
      const int seg = w * 4 + j;
      const int c = seg * 64 + lane;
      const int d = c >> 3;
      const int cc = (c & 7) ^ (d & 7);
      gload16(vt + (size_t)((b * 4 + kh) * 128 + d) * 2048 + kv0s + cc * 8,
              &Vs[bufsel][seg * 512]);
    }
  };

  const int ntiles = q0 / 64 + 2;

  STAGE(0, 0);
  asm volatile("s_waitcnt vmcnt(0)" ::: "memory");
  __syncthreads();

  for (int t = 0; t < ntiles; t++) {
    const int cur = t & 1;
    if (t + 1 < ntiles) STAGE(t + 1, cur ^ 1);   // prefetch overlaps compute

    const int kv0 = t * 64;
    if (kv0 <= qw0 + 31) {                       // wave-uniform: skip fully-masked
      f32x4 sf[2][4];
#pragma unroll
      for (int m = 0; m < 2; m++)
#pragma unroll
        for (int n = 0; n < 4; n++)
#pragma unroll
          for (int i = 0; i < 4; i++) sf[m][n][i] = 0.f;

      __builtin_amdgcn_s_setprio(1);
#pragma unroll
      for (int kk = 0; kk < 4; kk++) {           // S = Q K^T
        short8 kfr[4];
#pragma unroll
        for (int n = 0; n < 4; n++) {
          const int row = n * 16 + l15;
          kfr[n] = *(const short8*)&Kt[cur][row * 128 + ((kk * 32 + z * 8) ^ ksw)];
        }
#pragma unroll
        for (int m = 0; m < 2; m++)
#pragma unroll
          for (int n = 0; n < 4; n++)
            sf[m][n] = mfma_bf16(qf[m][kk], kfr[n], sf[m][n]);
      }
      __builtin_amdgcn_s_setprio(0);

      u16* Pw = &Pl[w * 2048];
      const bool edge = (kv0 + 63 > qw0);        // wave-uniform: masking needed?
#pragma unroll
      for (int m = 0; m < 2; m++) {
#pragma unroll
        for (int i = 0; i < 4; i++) {
          const int rq = qw0 + m * 16 + z * 4 + i;
          if (edge) {
#pragma unroll
            for (int n = 0; n < 4; n++)
              if (kv0 + n * 16 + l15 > rq) sf[m][n][i] = -1e30f;
          }
          float mx = fmaxf(fmaxf(sf[m][0][i], sf[m][1][i]), fmaxf(sf[m][2][i], sf[m][3][i]));
          mx = fmaxf(mx, __shfl_xor(mx, 1));
          mx = fmaxf(mx, __shfl_xor(mx, 2));
          mx = fmaxf(mx, __shfl_xor(mx, 4));
          mx = fmaxf(mx, __shfl_xor(mx, 8));
          const bool grow = mx > mst[m][i];
          const float mn = grow ? mx : mst[m][i];
          float rs = 0.f;
#pragma unroll
          for (int n = 0; n < 4; n++) {
            const float p = __expf(sf[m][n][i] - mn);
            sf[m][n][i] = p;
            rs += p;
          }
          rs += __shfl_xor(rs, 1);
          rs += __shfl_xor(rs, 2);
          rs += __shfl_xor(rs, 4);
          rs += __shfl_xor(rs, 8);
          if (grow) {                            // defer-rescale: only on max growth
            const float al = __expf(mst[m][i] - mx);
            mst[m][i] = mx;
            lst[m][i] = lst[m][i] * al + rs;
#pragma unroll
            for (int n = 0; n < 8; n++) oacc[m][n][i] *= al;
          } else {
            lst[m][i] += rs;
          }
          const int prow = m * 16 + z * 4 + i;
          const int psw = ((z * 4 + i) & 7) << 3;
#pragma unroll
          for (int n = 0; n < 4; n++)
            Pw[prow * 64 + ((n * 16 + l15) ^ psw)] = f2bf(sf[m][n][i]);
        }
      }

      __builtin_amdgcn_s_setprio(1);
#pragma unroll
      for (int kk = 0; kk < 2; kk++) {           // O += P V
        short8 af[2], vf[8];
#pragma unroll
        for (int m = 0; m < 2; m++) {
          const int row = m * 16 + l15;
          af[m] = *(const short8*)&Pw[row * 64 + ((kk * 32 + z * 8) ^ ksw)];
        }
#pragma unroll
        for (int n = 0; n < 8; n++) {
          const int row = n * 16 + l15;
          vf[n] = *(const short8*)&Vs[cur][row * 64 + ((kk * 32 + z * 8) ^ ksw)];
        }
#pragma unroll
        for (int m = 0; m < 2; m++)
#pragma unroll
          for (int n = 0; n < 8; n++)
            oacc[m][n] = mfma_bf16(af[m], vf[n], oacc[m][n]);
      }
      __builtin_amdgcn_s_setprio(0);
    }

    asm volatile("s_waitcnt vmcnt(0)" ::: "memory");
    __syncthreads();                             // single barrier per tile
  }

#pragma unroll
  for (int m = 0; m < 2; m++)
#pragma unroll
    for (int i = 0; i < 4; i++) {
      const float inv = 1.0f / lst[m][i];
      const int rq = qw0 + m * 16 + z * 4 + i;
      u16* orow = &ob[(size_t)(b * 2048 + rq) * 2048 + h * 128];
#pragma unroll
      for (int n = 0; n < 8; n++)
        orow[n * 16 + l15] = f2bf(oacc[m][n][i] * inv);
    }
}

// ------------------------------------------------------------------------------
extern "C" void kernel_launch(void* const* d_in, const int* in_sizes, int n_in,
                              void* d_out, int out_size, void* d_ws, size_t ws_size,
                              hipStream_t stream) {
  (void)in_sizes; (void)n_in; (void)out_size; (void)ws_size;
  const float* x     = (const float*)d_in[0];
  const float* ln1_g = (const float*)d_in[1];
  const float* ln1_b = (const float*)d_in[2];
  const float* wq    = (const float*)d_in[3];
  const float* bq    = (const float*)d_in[4];
  const float* wk    = (const float*)d_in[5];
  const float* bk    = (const float*)d_in[6];
  const float* wv    = (const float*)d_in[7];
  const float* bv    = (const float*)d_in[8];
  const float* wo    = (const float*)d_in[9];
  const float* bo    = (const float*)d_in[10];
  const float* ln2_g = (const float*)d_in[11];
  const float* ln2_b = (const float*)d_in[12];
  const float* wu    = (const float*)d_in[13];
  const float* bu    = (const float*)d_in[14];
  const float* wd    = (const float*)d_in[15];
  const float* bd    = (const float*)d_in[16];
  float* out = (float*)d_out;

  char* p = (char*)d_ws;
  u16* wqT = (u16*)p; p += (size_t)2048 * 2048 * 2;
  u16* wkT = (u16*)p; p += (size_t)512 * 2048 * 2;
  u16* wvT = (u16*)p; p += (size_t)512 * 2048 * 2;
  u16* woT = (u16*)p; p += (size_t)2048 * 2048 * 2;
  u16* wuT = (u16*)p; p += (size_t)8192 * 2048 * 2;
  u16* wdT = (u16*)p; p += (size_t)2048 * 8192 * 2;
  u16* x1  = (u16*)p; p += (size_t)4096 * 2048 * 2;   // reused as attention output
  u16* qbuf= (u16*)p; p += (size_t)4096 * 2048 * 2;   // reused as x2 (post-LN2)
  u16* kbuf= (u16*)p; p += (size_t)4096 * 512 * 2;
  u16* vtb = (u16*)p; p += (size_t)4096 * 512 * 2;    // V^T layout [b][kh][d][s]
  u16* hb  = (u16*)p; p += (size_t)4096 * 8192 * 2;
  u16* ob  = x1;
  u16* x2  = qbuf;

  // weight transpose+cast (B^T layout so GEMM operands are K-contiguous)
  transpose_cvt<<<dim3(64, 64),  256, 0, stream>>>(wq, wqT, 2048, 2048);
  transpose_cvt<<<dim3(16, 64),  256, 0, stream>>>(wk, wkT, 2048, 512);
  transpose_cvt<<<dim3(16, 64),  256, 0, stream>>>(wv, wvT, 2048, 512);
  transpose_cvt<<<dim3(64, 64),  256, 0, stream>>>(wo, woT, 2048, 2048);
  transpose_cvt<<<dim3(256, 64), 256, 0, stream>>>(wu, wuT, 2048, 8192);
  transpose_cvt<<<dim3(64, 256), 256, 0, stream>>>(wd, wdT, 8192, 2048);

  ln_kernel<<<4096, 256, 0, stream>>>(x, ln1_g, ln1_b, x1);

  gemm256<0, 128, 2048, 2048><<<256, 512, 0, stream>>>(x1, wqT, bq, nullptr, qbuf, nullptr);
  gemm_bt<1, 512, 2048><<<dim3(4, 32), 256, 0, stream>>>(x1, wkT, bk, kbuf);
  gemm_bt<2, 512, 2048><<<dim3(4, 32), 256, 0, stream>>>(x1, wvT, bv, vtb);

  attn_kernel<<<512, 256, 0, stream>>>(qbuf, kbuf, vtb, ob);

  gemm256<3, 128, 2048, 2048><<<256, 512, 0, stream>>>(ob, woT, bo, x, nullptr, out);

  ln_kernel<<<4096, 256, 0, stream>>>(out, ln2_g, ln2_b, x2);

  gemm256<4, 256, 8192, 2048><<<512, 512, 0, stream>>>(x2, wuT, bu, nullptr, hb, nullptr);
  gemm256<5, 128, 2048, 8192><<<256, 512, 0, stream>>>(hb, wdT, bd, nullptr, nullptr, out);
}

// Round 5
// 745.154 us; speedup vs baseline: 1.1637x; 1.1637x over previous
//
#include <hip/hip_runtime.h>
#include <hip/hip_bf16.h>
#include <cstdint>
#include <math.h>

// Problem constants: B=2,S=2048,E=2048,H=16,KH=4,G=4,D=128,F=8192, M=B*S=4096
typedef unsigned short u16;
using f32x4   = __attribute__((ext_vector_type(4))) float;
using short8  = __attribute__((ext_vector_type(8))) short;
using short4v = __attribute__((ext_vector_type(4))) short;

#define DEV static __device__ __forceinline__

DEV u16 f2bf(float f) {  // RNE f32 -> bf16
  union { float f; unsigned u; } v; v.f = f;
  unsigned r = v.u + 0x7fffu + ((v.u >> 16) & 1u);
  return (u16)(r >> 16);
}

DEV f32x4 mfma_bf16(short8 a, short8 b, f32x4 c) {
  return __builtin_amdgcn_mfma_f32_16x16x32_bf16(a, b, c, 0, 0, 0);
}

DEV void gload16(const void* g, void* l) {  // async global->LDS, 16B/lane, LDS base wave-uniform
  __builtin_amdgcn_global_load_lds((const __attribute__((address_space(1))) void*)g,
                                   (__attribute__((address_space(3))) void*)l,
                                   16, 0, 0);
}

// ---------------- transpose + f32->bf16 convert: out[n][k] = bf16(in[k][n]) ----
__global__ __launch_bounds__(256) void transpose_cvt(
    const float* __restrict__ in, u16* __restrict__ out, int K, int N)
{
  __shared__ float tile[32][33];
  const int n0 = blockIdx.x * 32, k0 = blockIdx.y * 32;
  const int c = threadIdx.x & 31, r = threadIdx.x >> 5;  // r in 0..7
#pragma unroll
  for (int i = 0; i < 4; i++) {
    const int row = r + i * 8;
    tile[row][c] = in[(size_t)(k0 + row) * N + n0 + c];
  }
  __syncthreads();
#pragma unroll
  for (int i = 0; i < 4; i++) {
    const int row = r + i * 8;
    out[(size_t)(n0 + row) * K + k0 + c] = f2bf(tile[c][row]);
  }
}

// ---------------- LayerNorm (f32 in, bf16 out), one row (2048) per block ------
__global__ __launch_bounds__(256) void ln_kernel(
    const float* __restrict__ x, const float* __restrict__ g,
    const float* __restrict__ bt, u16* __restrict__ out)
{
  __shared__ float red1[4], red2[4];
  const int row = blockIdx.x;
  const int t = threadIdx.x;
  const int lane = t & 63, w = t >> 6;
  const float* xr = x + (size_t)row * 2048 + t * 8;
  float v[8];
  {
    const float4* p4 = (const float4*)xr;
    float4 a = p4[0], b = p4[1];
    v[0] = a.x; v[1] = a.y; v[2] = a.z; v[3] = a.w;
    v[4] = b.x; v[5] = b.y; v[6] = b.z; v[7] = b.w;
  }
  float s = 0.f;
#pragma unroll
  for (int j = 0; j < 8; j++) s += v[j];
#pragma unroll
  for (int m = 1; m < 64; m <<= 1) s += __shfl_xor(s, m);
  if (lane == 0) red1[w] = s;
  __syncthreads();
  const float mu = (red1[0] + red1[1] + red1[2] + red1[3]) * (1.f / 2048.f);
  float q = 0.f;
#pragma unroll
  for (int j = 0; j < 8; j++) { v[j] -= mu; q += v[j] * v[j]; }
#pragma unroll
  for (int m = 1; m < 64; m <<= 1) q += __shfl_xor(q, m);
  if (lane == 0) red2[w] = q;
  __syncthreads();
  const float rstd = rsqrtf((red2[0] + red2[1] + red2[2] + red2[3]) * (1.f / 2048.f) + 1e-5f);
  const float4* g4 = (const float4*)(g + t * 8);
  const float4* b4 = (const float4*)(bt + t * 8);
  float4 ga = g4[0], gb = g4[1], ba = b4[0], bb = b4[1];
  float gg[8] = {ga.x, ga.y, ga.z, ga.w, gb.x, gb.y, gb.z, gb.w};
  float bbv[8] = {ba.x, ba.y, ba.z, ba.w, bb.x, bb.y, bb.z, bb.w};
  short8 o;
#pragma unroll
  for (int j = 0; j < 8; j++) o[j] = (short)f2bf(v[j] * rstd * gg[j] + bbv[j]);
  *(short8*)&out[(size_t)row * 2048 + t * 8] = o;
}

// ---------------- small GEMM (K/V, N=512): 128x128, 4 waves, 2-barrier -------
// MODE: 1=K(bias,bf16) 2=V(bias, write transposed [d][s])
template<int MODE, int N, int K>
__global__ void __launch_bounds__(256) gemm_bt(
    const u16* __restrict__ A, const u16* __restrict__ Bt,
    const float* __restrict__ bias,
    u16* __restrict__ out_bf)
{
  __shared__ u16 As[128 * 64];
  __shared__ u16 Bs[128 * 64];
  const int m0 = blockIdx.y * 128;
  const int n0 = blockIdx.x * 128;
  const int tid = threadIdx.x;
  const int lane = tid & 63, w = tid >> 6;
  const int wm = w >> 1, wn = w & 1;
  const int z = lane >> 4, l15 = lane & 15;

  f32x4 acc[4][4];
#pragma unroll
  for (int m = 0; m < 4; m++)
#pragma unroll
    for (int n = 0; n < 4; n++)
#pragma unroll
      for (int i = 0; i < 4; i++) acc[m][n][i] = 0.f;

  for (int k0 = 0; k0 < K; k0 += 64) {
#pragma unroll
    for (int j = 0; j < 4; j++) {
      const int seg = w * 4 + j;
      const int c = seg * 64 + lane;
      const int r = c >> 3;
      const int cc = (c & 7) ^ (r & 7);           // source pre-swizzle
      gload16(A + (size_t)(m0 + r) * K + k0 + cc * 8, &As[seg * 512]);
    }
#pragma unroll
    for (int j = 0; j < 4; j++) {
      const int seg = w * 4 + j;
      const int c = seg * 64 + lane;
      const int r = c >> 3;
      const int cc = (c & 7) ^ (r & 7);
      gload16(Bt + (size_t)(n0 + r) * K + k0 + cc * 8, &Bs[seg * 512]);
    }
    asm volatile("s_waitcnt vmcnt(0)" ::: "memory");
    __syncthreads();

#pragma unroll
    for (int kk = 0; kk < 2; kk++) {
      short8 af[4], bfr[4];
#pragma unroll
      for (int m = 0; m < 4; m++) {
        const int row = wm * 64 + m * 16 + l15;
        const int off = row * 64 + ((kk * 32 + z * 8) ^ ((row & 7) << 3));
        af[m] = *(const short8*)&As[off];
      }
#pragma unroll
      for (int n = 0; n < 4; n++) {
        const int row = wn * 64 + n * 16 + l15;
        const int off = row * 64 + ((kk * 32 + z * 8) ^ ((row & 7) << 3));
        bfr[n] = *(const short8*)&Bs[off];
      }
#pragma unroll
      for (int m = 0; m < 4; m++)
#pragma unroll
        for (int n = 0; n < 4; n++)
          acc[m][n] = mfma_bf16(af[m], bfr[n], acc[m][n]);
    }
    __syncthreads();
  }

#pragma unroll
  for (int m = 0; m < 4; m++) {
    const int row0 = m0 + wm * 64 + m * 16 + z * 4;
#pragma unroll
    for (int n = 0; n < 4; n++) {
      const int col = n0 + wn * 64 + n * 16 + l15;
      f32x4 v = acc[m][n];
      const float bb = bias[col];
      if constexpr (MODE == 1) {
#pragma unroll
        for (int i = 0; i < 4; i++)
          out_bf[(size_t)(row0 + i) * N + col] = f2bf(v[i] + bb);
      } else {
        const int bidx = row0 >> 11, sidx = row0 & 2047;
        const int kh = col >> 7, d = col & 127;
        short4v p;
#pragma unroll
        for (int i = 0; i < 4; i++) p[i] = (short)f2bf(v[i] + bb);
        *(short4v*)&out_bf[(size_t)((bidx * 4 + kh) * 128 + d) * 2048 + sidx] = p;
      }
    }
  }
}

// ---------------- big GEMM: 128x128, 4 waves, double-buffered LDS, ONE barrier
// per K-tile (T3-minimum recipe): STAGE(t+1) -> ds_read(cur)+MFMA -> vmcnt(0)
// +barrier. Prefetched loads get the whole MFMA duration in flight. Bijective
// XCD swizzle on a 1D grid (n-fastest within chunk -> A-panel L2 residency).
// MODE: 0=Q(bias,*scale,bf16) 3=O(bias+resid,f32) 4=U(bias+gelu,bf16) 5=D(bias+accum,f32)
template<int MODE, int N, int K>
__global__ void __launch_bounds__(256) gemm_db(
    const u16* __restrict__ A, const u16* __restrict__ Bt,
    const float* __restrict__ bias, const float* __restrict__ resid,
    u16* __restrict__ out_bf, float* __restrict__ out_f)
{
  __shared__ u16 As[2][128 * 64];
  __shared__ u16 Bs[2][128 * 64];
  constexpr int TN = N / 128;
  constexpr int NWG = 32 * TN;          // M=4096 -> 32 m-tiles
  constexpr int CPX = NWG / 8;
  constexpr int NT = K / 64;

  const int bid = blockIdx.x;
  const int wg = (bid & 7) * CPX + (bid >> 3);   // XCD-contiguous chunks
  const int m0 = (wg / TN) * 128;
  const int n0 = (wg % TN) * 128;
  const int tid = threadIdx.x;
  const int lane = tid & 63, w = tid >> 6;
  const int wm = w >> 1, wn = w & 1;
  const int z = lane >> 4, l15 = lane & 15;

  f32x4 acc[4][4];
#pragma unroll
  for (int m = 0; m < 4; m++)
#pragma unroll
    for (int n = 0; n < 4; n++)
#pragma unroll
      for (int i = 0; i < 4; i++) acc[m][n][i] = 0.f;

  auto stage = [&](int k0, int buf) {
#pragma unroll
    for (int j = 0; j < 4; j++) {
      const int seg = w * 4 + j;
      const int c = seg * 64 + lane;
      const int r = c >> 3;
      const int cc = (c & 7) ^ (r & 7);           // source pre-swizzle
      gload16(A + (size_t)(m0 + r) * K + k0 + cc * 8, &As[buf][seg * 512]);
    }
#pragma unroll
    for (int j = 0; j < 4; j++) {
      const int seg = w * 4 + j;
      const int c = seg * 64 + lane;
      const int r = c >> 3;
      const int cc = (c & 7) ^ (r & 7);
      gload16(Bt + (size_t)(n0 + r) * K + k0 + cc * 8, &Bs[buf][seg * 512]);
    }
  };

  stage(0, 0);
  asm volatile("s_waitcnt vmcnt(0)" ::: "memory");
  __syncthreads();

  int cur = 0;
  for (int t = 0; t < NT; t++) {
    if (t + 1 < NT) stage((t + 1) * 64, cur ^ 1);  // prefetch overlaps MFMA

#pragma unroll
    for (int kk = 0; kk < 2; kk++) {
      short8 af[4], bfr[4];
#pragma unroll
      for (int m = 0; m < 4; m++) {
        const int row = wm * 64 + m * 16 + l15;
        const int off = row * 64 + ((kk * 32 + z * 8) ^ ((row & 7) << 3));
        af[m] = *(const short8*)&As[cur][off];
      }
#pragma unroll
      for (int n = 0; n < 4; n++) {
        const int row = wn * 64 + n * 16 + l15;
        const int off = row * 64 + ((kk * 32 + z * 8) ^ ((row & 7) << 3));
        bfr[n] = *(const short8*)&Bs[cur][off];
      }
      __builtin_amdgcn_s_setprio(1);
#pragma unroll
      for (int m = 0; m < 4; m++)
#pragma unroll
        for (int n = 0; n < 4; n++)
          acc[m][n] = mfma_bf16(af[m], bfr[n], acc[m][n]);
      __builtin_amdgcn_s_setprio(0);
    }

    asm volatile("s_waitcnt vmcnt(0)" ::: "memory");
    __syncthreads();                               // ONE barrier per K-tile
    cur ^= 1;
  }

#pragma unroll
  for (int m = 0; m < 4; m++) {
    const int row0 = m0 + wm * 64 + m * 16 + z * 4;
#pragma unroll
    for (int n = 0; n < 4; n++) {
      const int col = n0 + wn * 64 + n * 16 + l15;
      f32x4 v = acc[m][n];
      const float bb = bias[col];
      if constexpr (MODE == 0) {
#pragma unroll
        for (int i = 0; i < 4; i++)
          out_bf[(size_t)(row0 + i) * N + col] = f2bf((v[i] + bb) * 0.08838834764831845f);
      } else if constexpr (MODE == 3) {
#pragma unroll
        for (int i = 0; i < 4; i++) {
          const size_t idx = (size_t)(row0 + i) * N + col;
          out_f[idx] = v[i] + bb + resid[idx];
        }
      } else if constexpr (MODE == 4) {
#pragma unroll
        for (int i = 0; i < 4; i++) {
          const float xx = v[i] + bb;
          out_bf[(size_t)(row0 + i) * N + col] =
              f2bf(0.5f * xx * (1.f + erff(xx * 0.70710678118654752f)));
        }
      } else {
#pragma unroll
        for (int i = 0; i < 4; i++) {
          const size_t idx = (size_t)(row0 + i) * N + col;
          out_f[idx] = v[i] + bb + out_f[idx];
        }
      }
    }
  }
}

// ---------------- Flash attention, causal, GQA. 128 q-rows/block, 4 waves -----
__global__ void __launch_bounds__(256) attn_kernel(
    const u16* __restrict__ qb, const u16* __restrict__ kb,
    const u16* __restrict__ vt, u16* __restrict__ ob)
{
  __shared__ u16 Kt[2][64 * 128];
  __shared__ u16 Vs[2][128 * 64];
  __shared__ u16 Pl[4 * 32 * 64];

  const int idx = blockIdx.x;
  const int xcd = idx & 7;
  const int u = (idx >> 3) & 31;
  const int half = idx >> 8;
  const int bh = xcd * 4 + (u & 3);       // 4 bh per XCD -> one (b,kh) KV set
  const int qh = u >> 2;                  // 0..7
  const int qt = half ? (15 - qh) : qh;   // complementary pairing: i <-> i+256

  const int b = bh >> 4, h = bh & 15, kh = h >> 2;
  const int q0 = qt * 128;
  const int tid = threadIdx.x, lane = tid & 63, w = tid >> 6;
  const int z = lane >> 4, l15 = lane & 15;
  const int qw0 = q0 + w * 32;
  const int ksw = (l15 & 7) << 3;         // read-side XOR swizzle

  short8 qf[2][4];
#pragma unroll
  for (int m = 0; m < 2; m++)
#pragma unroll
    for (int kk = 0; kk < 4; kk++)
      qf[m][kk] = *(const short8*)&qb[(size_t)(b * 2048 + qw0 + m * 16 + l15) * 2048 +
                                      h * 128 + kk * 32 + z * 8];

  f32x4 oacc[2][8];
#pragma unroll
  for (int m = 0; m < 2; m++)
#pragma unroll
    for (int n = 0; n < 8; n++)
#pragma unroll
      for (int i = 0; i < 4; i++) oacc[m][n][i] = 0.f;
  float mst[2][4], lst[2][4];
#pragma unroll
  for (int m = 0; m < 2; m++)
#pragma unroll
    for (int i = 0; i < 4; i++) { mst[m][i] = -1e30f; lst[m][i] = 0.f; }

  auto STAGE = [&](int tt, int bufsel) {
    const int kv0s = tt * 64;
#pragma unroll
    for (int j = 0; j < 4; j++) {               // K tile (rows=kv, 128 d)
      const int seg = w * 4 + j;
      const int c = seg * 64 + lane;
      const int r = c >> 4;
      const int cc = (c & 15) ^ (r & 7);
      gload16(kb + (size_t)(b * 2048 + kv0s + r) * 512 + kh * 128 + cc * 8,
              &Kt[bufsel][seg * 512]);
    }
#pragma unroll
    for (int j = 0; j < 4; j++) {               // V^T tile (rows=d, 64 kv)
      const int seg = w * 4 + j;
      const int c = seg * 64 + lane;
      const int d = c >> 3;
      const int cc = (c & 7) ^ (d & 7);
      gload16(vt + (size_t)((b * 4 + kh) * 128 + d) * 2048 + kv0s + cc * 8,
              &Vs[bufsel][seg * 512]);
    }
  };

  const int ntiles = q0 / 64 + 2;

  STAGE(0, 0);
  asm volatile("s_waitcnt vmcnt(0)" ::: "memory");
  __syncthreads();

  for (int t = 0; t < ntiles; t++) {
    const int cur = t & 1;
    if (t + 1 < ntiles) STAGE(t + 1, cur ^ 1);   // prefetch overlaps compute

    const int kv0 = t * 64;
    if (kv0 <= qw0 + 31) {                       // wave-uniform: skip fully-masked
      f32x4 sf[2][4];
#pragma unroll
      for (int m = 0; m < 2; m++)
#pragma unroll
        for (int n = 0; n < 4; n++)
#pragma unroll
          for (int i = 0; i < 4; i++) sf[m][n][i] = 0.f;

      __builtin_amdgcn_s_setprio(1);
#pragma unroll
      for (int kk = 0; kk < 4; kk++) {           // S = Q K^T
        short8 kfr[4];
#pragma unroll
        for (int n = 0; n < 4; n++) {
          const int row = n * 16 + l15;
          kfr[n] = *(const short8*)&Kt[cur][row * 128 + ((kk * 32 + z * 8) ^ ksw)];
        }
#pragma unroll
        for (int m = 0; m < 2; m++)
#pragma unroll
          for (int n = 0; n < 4; n++)
            sf[m][n] = mfma_bf16(qf[m][kk], kfr[n], sf[m][n]);
      }
      __builtin_amdgcn_s_setprio(0);

      u16* Pw = &Pl[w * 2048];
      const bool edge = (kv0 + 63 > qw0);        // wave-uniform: masking needed?
#pragma unroll
      for (int m = 0; m < 2; m++) {
#pragma unroll
        for (int i = 0; i < 4; i++) {
          const int rq = qw0 + m * 16 + z * 4 + i;
          if (edge) {
#pragma unroll
            for (int n = 0; n < 4; n++)
              if (kv0 + n * 16 + l15 > rq) sf[m][n][i] = -1e30f;
          }
          float mx = fmaxf(fmaxf(sf[m][0][i], sf[m][1][i]), fmaxf(sf[m][2][i], sf[m][3][i]));
          mx = fmaxf(mx, __shfl_xor(mx, 1));
          mx = fmaxf(mx, __shfl_xor(mx, 2));
          mx = fmaxf(mx, __shfl_xor(mx, 4));
          mx = fmaxf(mx, __shfl_xor(mx, 8));
          const bool grow = mx > mst[m][i];
          const float mn = grow ? mx : mst[m][i];
          float rs = 0.f;
#pragma unroll
          for (int n = 0; n < 4; n++) {
            const float p = __expf(sf[m][n][i] - mn);
            sf[m][n][i] = p;
            rs += p;
          }
          rs += __shfl_xor(rs, 1);
          rs += __shfl_xor(rs, 2);
          rs += __shfl_xor(rs, 4);
          rs += __shfl_xor(rs, 8);
          if (grow) {                            // defer-rescale: only on max growth
            const float al = __expf(mst[m][i] - mx);
            mst[m][i] = mx;
            lst[m][i] = lst[m][i] * al + rs;
#pragma unroll
            for (int n = 0; n < 8; n++) oacc[m][n][i] *= al;
          } else {
            lst[m][i] += rs;
          }
          const int prow = m * 16 + z * 4 + i;
          const int psw = ((z * 4 + i) & 7) << 3;
#pragma unroll
          for (int n = 0; n < 4; n++)
            Pw[prow * 64 + ((n * 16 + l15) ^ psw)] = f2bf(sf[m][n][i]);
        }
      }

      __builtin_amdgcn_s_setprio(1);
#pragma unroll
      for (int kk = 0; kk < 2; kk++) {           // O += P V
        short8 af[2], vf[8];
#pragma unroll
        for (int m = 0; m < 2; m++) {
          const int row = m * 16 + l15;
          af[m] = *(const short8*)&Pw[row * 64 + ((kk * 32 + z * 8) ^ ksw)];
        }
#pragma unroll
        for (int n = 0; n < 8; n++) {
          const int row = n * 16 + l15;
          vf[n] = *(const short8*)&Vs[cur][row * 64 + ((kk * 32 + z * 8) ^ ksw)];
        }
#pragma unroll
        for (int m = 0; m < 2; m++)
#pragma unroll
          for (int n = 0; n < 8; n++)
            oacc[m][n] = mfma_bf16(af[m], vf[n], oacc[m][n]);
      }
      __builtin_amdgcn_s_setprio(0);
    }

    asm volatile("s_waitcnt vmcnt(0)" ::: "memory");
    __syncthreads();                             // single barrier per tile
  }

#pragma unroll
  for (int m = 0; m < 2; m++)
#pragma unroll
    for (int i = 0; i < 4; i++) {
      const float inv = 1.0f / lst[m][i];
      const int rq = qw0 + m * 16 + z * 4 + i;
      u16* orow = &ob[(size_t)(b * 2048 + rq) * 2048 + h * 128];
#pragma unroll
      for (int n = 0; n < 8; n++)
        orow[n * 16 + l15] = f2bf(oacc[m][n][i] * inv);
    }
}

// ------------------------------------------------------------------------------
extern "C" void kernel_launch(void* const* d_in, const int* in_sizes, int n_in,
                              void* d_out, int out_size, void* d_ws, size_t ws_size,
                              hipStream_t stream) {
  (void)in_sizes; (void)n_in; (void)out_size; (void)ws_size;
  const float* x     = (const float*)d_in[0];
  const float* ln1_g = (const float*)d_in[1];
  const float* ln1_b = (const float*)d_in[2];
  const float* wq    = (const float*)d_in[3];
  const float* bq    = (const float*)d_in[4];
  const float* wk    = (const float*)d_in[5];
  const float* bk    = (const float*)d_in[6];
  const float* wv    = (const float*)d_in[7];
  const float* bv    = (const float*)d_in[8];
  const float* wo    = (const float*)d_in[9];
  const float* bo    = (const float*)d_in[10];
  const float* ln2_g = (const float*)d_in[11];
  const float* ln2_b = (const float*)d_in[12];
  const float* wu    = (const float*)d_in[13];
  const float* bu    = (const float*)d_in[14];
  const float* wd    = (const float*)d_in[15];
  const float* bd    = (const float*)d_in[16];
  float* out = (float*)d_out;

  char* p = (char*)d_ws;
  u16* wqT = (u16*)p; p += (size_t)2048 * 2048 * 2;
  u16* wkT = (u16*)p; p += (size_t)512 * 2048 * 2;
  u16* wvT = (u16*)p; p += (size_t)512 * 2048 * 2;
  u16* woT = (u16*)p; p += (size_t)2048 * 2048 * 2;
  u16* wuT = (u16*)p; p += (size_t)8192 * 2048 * 2;
  u16* wdT = (u16*)p; p += (size_t)2048 * 8192 * 2;
  u16* x1  = (u16*)p; p += (size_t)4096 * 2048 * 2;   // reused as attention output
  u16* qbuf= (u16*)p; p += (size_t)4096 * 2048 * 2;   // reused as x2 (post-LN2)
  u16* kbuf= (u16*)p; p += (size_t)4096 * 512 * 2;
  u16* vtb = (u16*)p; p += (size_t)4096 * 512 * 2;    // V^T layout [b][kh][d][s]
  u16* hb  = (u16*)p; p += (size_t)4096 * 8192 * 2;
  u16* ob  = x1;
  u16* x2  = qbuf;

  // weight transpose+cast (B^T layout so GEMM operands are K-contiguous)
  transpose_cvt<<<dim3(64, 64),  256, 0, stream>>>(wq, wqT, 2048, 2048);
  transpose_cvt<<<dim3(16, 64),  256, 0, stream>>>(wk, wkT, 2048, 512);
  transpose_cvt<<<dim3(16, 64),  256, 0, stream>>>(wv, wvT, 2048, 512);
  transpose_cvt<<<dim3(64, 64),  256, 0, stream>>>(wo, woT, 2048, 2048);
  transpose_cvt<<<dim3(256, 64), 256, 0, stream>>>(wu, wuT, 2048, 8192);
  transpose_cvt<<<dim3(64, 256), 256, 0, stream>>>(wd, wdT, 8192, 2048);

  ln_kernel<<<4096, 256, 0, stream>>>(x, ln1_g, ln1_b, x1);

  gemm_db<0, 2048, 2048><<<512, 256, 0, stream>>>(x1, wqT, bq, nullptr, qbuf, nullptr);
  gemm_bt<1, 512, 2048><<<dim3(4, 32), 256, 0, stream>>>(x1, wkT, bk, kbuf);
  gemm_bt<2, 512, 2048><<<dim3(4, 32), 256, 0, stream>>>(x1, wvT, bv, vtb);

  attn_kernel<<<512, 256, 0, stream>>>(qbuf, kbuf, vtb, ob);

  gemm_db<3, 2048, 2048><<<512, 256, 0, stream>>>(ob, woT, bo, x, nullptr, out);

  ln_kernel<<<4096, 256, 0, stream>>>(out, ln2_g, ln2_b, x2);

  gemm_db<4, 8192, 2048><<<2048, 256, 0, stream>>>(x2, wuT, bu, nullptr, hb, nullptr);
  gemm_db<5, 2048, 8192><<<512, 256, 0, stream>>>(hb, wdT, bd, nullptr, nullptr, out);
}